// Round 8
// baseline (191.865 us; speedup 1.0000x reference)
//
#include <hip/hip_runtime.h>

// Problem constants (reference: B=8, T=1024, C=768, NH=12)
constexpr int Bb  = 8;
constexpr int Tt  = 1024;
constexpr int Cc  = 768;
constexpr int NHh = 12;
constexpr int HS  = 64;        // head size
constexpr int C3  = 3 * Cc;    // 2304

typedef short bf16x8 __attribute__((ext_vector_type(8)));   // 8 bf16 bit-patterns (4 VGPRs)
typedef float f32x4  __attribute__((ext_vector_type(4)));

__device__ inline short bf16r(float f) {           // RNE f32 -> bf16 bits
    unsigned u = __float_as_uint(f);
    u += 0x7FFF + ((u >> 16) & 1);
    return (short)(u >> 16);
}
__device__ inline short bf16h(float f) {           // half-up (cheap, for P in (0,1])
    return (short)((__float_as_uint(f) + 0x8000u) >> 16);
}

// ---------------------------------------------------------------------------
// Fused prep: x fp32->bf16 convert, Wqkv / Wproj fp32->bf16 transpose.
// ---------------------------------------------------------------------------
__global__ __launch_bounds__(256)
void prep_all(const float* __restrict__ x, const float* __restrict__ Wqkv,
              const float* __restrict__ Wproj, short* __restrict__ xb,
              short* __restrict__ wqkvT, short* __restrict__ wprojT) {
    int bid = blockIdx.x;
    constexpr int XBLK = (Bb * Tt * Cc) / 1024;        // 6144
    constexpr int QT   = (C3 / 32) * (Cc / 32);        // 1728
    if (bid < XBLK) {
        const int i = (bid * 256 + threadIdx.x) * 4;
        float4 v = *(const float4*)(x + i);
        short4 o;
        o.x = bf16r(v.x); o.y = bf16r(v.y); o.z = bf16r(v.z); o.w = bf16r(v.w);
        *(short4*)(xb + i) = o;
        return;
    }
    bid -= XBLK;
    const float* src; short* dst; int C;
    if (bid < QT) { src = Wqkv;  dst = wqkvT;  C = C3; }
    else          { bid -= QT; src = Wproj; dst = wprojT; C = Cc; }
    const int tcx = bid % (C / 32), tcy = bid / (C / 32);
    __shared__ short tile[32][33];
    const int tx = threadIdx.x & 31, ty = threadIdx.x >> 5;   // ty 0..7
#pragma unroll
    for (int rr = 0; rr < 4; ++rr) {
        const int r = ty * 4 + rr;
        tile[r][tx] = bf16r(src[(size_t)(tcy * 32 + r) * C + tcx * 32 + tx]);
    }
    __syncthreads();
#pragma unroll
    for (int rr = 0; rr < 4; ++rr) {
        const int orow = ty * 4 + rr;   // output row = input col
        dst[(size_t)(tcx * 32 + orow) * Cc + tcy * 32 + tx] = tile[tx][orow];
    }
}

// ---------------------------------------------------------------------------
// V transpose: qkv V-third [b*T+t][h*64+d] -> vt[(bh*64+d)*T + t]
// ---------------------------------------------------------------------------
__global__ __launch_bounds__(256)
void transpose_v(const short* __restrict__ qkv, short* __restrict__ vt) {
    __shared__ short tile[64][65];
    const int bh = blockIdx.y;                 // b*NH + h
    const int b = bh / NHh, h = bh % NHh;
    const int t0 = blockIdx.x * 64;
    const int tx = threadIdx.x & 63, ty = threadIdx.x >> 6;   // ty 0..3
    const short* src = qkv + ((size_t)b * Tt + t0) * C3 + 2 * Cc + h * HS;
#pragma unroll
    for (int r = 0; r < 16; ++r)
        tile[ty * 16 + r][tx] = src[(size_t)(ty * 16 + r) * C3 + tx];
    __syncthreads();
    short* dst = vt + (size_t)bh * HS * Tt + t0;
#pragma unroll
    for (int r = 0; r < 16; ++r)
        dst[(size_t)(ty * 16 + r) * Tt + tx] = tile[tx][ty * 16 + r];
}

// ---------------------------------------------------------------------------
// bf16 MFMA GEMM, double-buffered LDS + XCD-aware block swizzle.
// C[M,N] = A[M,K] @ Bt[N,K]^T + bias.  Tile (MI*32) x 128, BK=32, 4 waves.
// Round-0 exact (VGPR 84).  OB: 1 -> bf16 output, 0 -> fp32 output.
// ---------------------------------------------------------------------------
template <int MI, int OB>
__global__ __launch_bounds__(256)
void gemm_mfma_bias(const short* __restrict__ A, const short* __restrict__ Bt,
                    const float* __restrict__ bias, void* __restrict__ Cout,
                    int M, int N, int K) {
    constexpr int TM = MI * 32;
    __shared__ __align__(16) short Als[2][TM * 32];    // [buf][row][k 0..31]
    __shared__ __align__(16) short Bls[2][128 * 32];

    const int t = threadIdx.x, w = t >> 6, lane = t & 63;

    // XCD swizzle
    const int flat = blockIdx.y * gridDim.x + blockIdx.x;
    const int mPer = gridDim.y >> 3;
    const int idx  = flat >> 3;
    const int my   = (flat & 7) * mPer + idx % mPer;
    const int nx   = idx / mPer;
    const int m0 = my * TM, n0 = nx * 128;

    const int sr = t >> 2;                          // 0..63
    const int lg = ((t & 3) ^ ((t >> 3) & 3)) * 8;  // logical granule (shorts)

    const short* Ag[MI / 2];
#pragma unroll
    for (int q = 0; q < MI / 2; ++q)
        Ag[q] = A + (size_t)(m0 + q * 64 + sr) * K + lg;
    const short* Bg[2];
#pragma unroll
    for (int q = 0; q < 2; ++q)
        Bg[q] = Bt + (size_t)(n0 + q * 64 + sr) * K + lg;

    const int wq = w * 1024;   // wave-uniform LDS byte offset within a 4-KB chunk

    const int wm = (w >> 1) * (MI * 16), wn = (w & 1) * 64;
    const int laneM = lane & 15, laneG = lane >> 4;
    const int kx = (laneG ^ ((laneM >> 1) & 3)) * 8;

    f32x4 acc[MI][4] = {};

    const int nk = K / 32;

    // prologue: stage tile 0 into buffer 0
#pragma unroll
    for (int q = 0; q < MI / 2; ++q)
        __builtin_amdgcn_global_load_lds(
            (const __attribute__((address_space(1))) void*)(Ag[q]),
            (__attribute__((address_space(3))) void*)((char*)&Als[0][0] + q * 4096 + wq), 16, 0, 0);
#pragma unroll
    for (int q = 0; q < 2; ++q)
        __builtin_amdgcn_global_load_lds(
            (const __attribute__((address_space(1))) void*)(Bg[q]),
            (__attribute__((address_space(3))) void*)((char*)&Bls[0][0] + q * 4096 + wq), 16, 0, 0);

    for (int kt = 0; kt < nk; ++kt) {
        __syncthreads();   // buf[kt&1] staged; buf[(kt+1)&1] reads (iter kt-1) done

        const short* Ab = &Als[kt & 1][0];
        const short* Bb = &Bls[kt & 1][0];
        bf16x8 af[MI], bfr[4];
#pragma unroll
        for (int i = 0; i < MI; ++i)
            af[i] = *(const bf16x8*)&Ab[(wm + i * 16 + laneM) * 32 + kx];
#pragma unroll
        for (int j = 0; j < 4; ++j)
            bfr[j] = *(const bf16x8*)&Bb[(wn + j * 16 + laneM) * 32 + kx];

        if (kt + 1 < nk) {   // prefetch next tile into the other buffer
            const int b = (kt + 1) & 1, ko = (kt + 1) * 32;
#pragma unroll
            for (int q = 0; q < MI / 2; ++q)
                __builtin_amdgcn_global_load_lds(
                    (const __attribute__((address_space(1))) void*)(Ag[q] + ko),
                    (__attribute__((address_space(3))) void*)((char*)&Als[b][0] + q * 4096 + wq), 16, 0, 0);
#pragma unroll
            for (int q = 0; q < 2; ++q)
                __builtin_amdgcn_global_load_lds(
                    (const __attribute__((address_space(1))) void*)(Bg[q] + ko),
                    (__attribute__((address_space(3))) void*)((char*)&Bls[b][0] + q * 4096 + wq), 16, 0, 0);
        }

#pragma unroll
        for (int i = 0; i < MI; ++i)
#pragma unroll
            for (int j = 0; j < 4; ++j)
                acc[i][j] = __builtin_amdgcn_mfma_f32_16x16x32_bf16(
                    af[i], bfr[j], acc[i][j], 0, 0, 0);
    }

    // epilogue: C/D mapping col = lane&15, row = (lane>>4)*4 + reg
    const int rowBase = m0 + wm + laneG * 4;
    const int colBase = n0 + wn + laneM;
#pragma unroll
    for (int j = 0; j < 4; ++j) {
        const int col = colBase + j * 16;
        const float bv = bias[col];
#pragma unroll
        for (int i = 0; i < MI; ++i) {
#pragma unroll
            for (int r = 0; r < 4; ++r) {
                const int row = rowBase + i * 16 + r;
                const float v = acc[i][j][r] + bv;
                if (OB) ((short*)Cout)[(size_t)row * N + col] = bf16r(v);
                else    ((float*)Cout)[(size_t)row * N + col] = v;
            }
        }
    }
}

// ---------------------------------------------------------------------------
// Flash causal attention, bf16 MFMA, double-buffered K/V staging.
//
// Round 8: 2 waves x 32 q-rows (was 4 waves x 16).  Evidence: r5/r6/r7 show
// attn ~95% stalled, occupancy-insensitive (r6: 3->5 blocks/CU = 0 effect),
// MFMA-count-insensitive (r6/r7) -> shared-resource bound: LDS BW (~96 KB
// through LDS per 64-key block-iter, ~18 us at the 69 TB/s ceiling, dominated
// by K/V fragment reads that all waves repeat).  Fix: each wave owns TWO
// 16-row MFMA groups (mg) and reads each K/V fragment ONCE into registers,
// reusing it for both mg -> K/V LDS read traffic per unit work halves
// (block-iter: 96 KB -> ~60 KB).  Same 64-row q-tiles, same (pi,15-pi)
// pairing (17 iters/block, perfect balance), 768 blocks of 128 threads,
// LDS 41.2 KB -> 3 blocks/CU (6 waves/CU -- acceptable per r6's null).
// Ones-MFMA l (r4 best).  T5 setprio around MFMA clusters.
// Fixed-stabilizer softmax (scores ~N(0,0.31^2), |s|<4 at >10 sigma).
// ---------------------------------------------------------------------------
__global__ __launch_bounds__(128)
void flash_attn(const short* __restrict__ qkv, const short* __restrict__ vt,
                short* __restrict__ y) {
    const int bh = blockIdx.x % (Bb * NHh);
    const int pi = blockIdx.x / (Bb * NHh);    // 0..7
    const int h  = bh % NHh, b = bh / NHh;
    const int t = threadIdx.x, w = t >> 6, lane = t & 63;   // w in {0,1}
    const int laneM = lane & 15, laneG = lane >> 4;

    __shared__ short Kls[2][64 * 64];    // [buf][key][d], granule-swizzled
    __shared__ short Vls[2][64 * 64];    // [buf][d][key], granule-swizzled
    __shared__ short Pls[2][32 * 72];    // per-wave P tile [qrow 0..31][key]

    const size_t bT = (size_t)b * Tt;

    bf16x8 onesb;
#pragma unroll
    for (int j = 0; j < 8; ++j) onesb[j] = (short)0x3F80;   // bf16 1.0

    // staging: 8 insts of 2 KB (128 thr x 16 B); inst covers 16 rows.
    const int srow = t >> 3;                  // 0..15
    const int gpos = t & 7;
    const int gs0 = (gpos ^ (srow & 7)) * 8;  // swizzled granule offset

    const short* Kbase = qkv + (bT + srow) * C3 + Cc + h * HS + gs0;
    const short* Vbase = vt + ((size_t)bh * HS + srow) * Tt + gs0;

    auto stage = [&](int kt, int buf) {
        const short* Kg = Kbase + (size_t)kt * 64 * C3;
        const short* Vg = Vbase + kt * 64;
        char* KB = (char*)&Kls[buf][0] + w * 1024;
        char* VB = (char*)&Vls[buf][0] + w * 1024;
#pragma unroll
        for (int i = 0; i < 4; ++i)
            __builtin_amdgcn_global_load_lds(
                (const __attribute__((address_space(1))) void*)(Kg + (size_t)i * 16 * C3),
                (__attribute__((address_space(3))) void*)(KB + i * 2048), 16, 0, 0);
#pragma unroll
        for (int i = 0; i < 4; ++i)
            __builtin_amdgcn_global_load_lds(
                (const __attribute__((address_space(1))) void*)(Vg + (size_t)i * 16 * Tt),
                (__attribute__((address_space(3))) void*)(VB + i * 2048), 16, 0, 0);
    };

    constexpr float cexp = 0.18033688f;       // (1/sqrt(64)) * log2(e)
    constexpr float moff = -5.7707801f;       // -4 * log2(e)

#pragma unroll 1
    for (int sub = 0; sub < 2; ++sub) {
        const int qt = sub ? (15 - pi) : pi;
        const int q0 = qt * 64;

        // Q rows: q0 + w*32 + mg*16 + laneM
        const short* qp0 = qkv + (bT + q0 + w * 32 + laneM) * C3 + h * HS;
        const short* qp1 = qp0 + (size_t)16 * C3;
        bf16x8 qf[2][2];
        qf[0][0] = *(const bf16x8*)(qp0 + laneG * 8);
        qf[0][1] = *(const bf16x8*)(qp0 + 32 + laneG * 8);
        qf[1][0] = *(const bf16x8*)(qp1 + laneG * 8);
        qf[1][1] = *(const bf16x8*)(qp1 + 32 + laneG * 8);

        f32x4 oacc[2][4] = {};
        f32x4 lacc[2]    = {};

        __syncthreads();       // prior sub's reads of buf0 done before restage
        stage(0, 0);           // prologue

#pragma unroll 1
        for (int kt = 0; kt <= qt; ++kt) {
            __syncthreads();   // buf[kt&1] staged; other buf's reads done
            if (kt < qt) stage(kt + 1, (kt + 1) & 1);

            const short* Kb = &Kls[kt & 1][0];
            const short* Vb = &Vls[kt & 1][0];

            // --- K fragments: read ONCE, reuse for both mg ------------------
            bf16x8 kf[2][4];
#pragma unroll
            for (int ks = 0; ks < 2; ++ks)
#pragma unroll
                for (int nb = 0; nb < 4; ++nb) {
                    const int key = nb * 16 + laneM;
                    kf[ks][nb] = *(const bf16x8*)
                        &Kb[key * 64 + (((ks << 2) + laneG) ^ (key & 7)) * 8];
                }

            // --- S = Q K^T for both 16-row groups ---------------------------
            f32x4 sacc[2][4] = {};
            __builtin_amdgcn_s_setprio(1);
#pragma unroll
            for (int mg = 0; mg < 2; ++mg)
#pragma unroll
                for (int ks = 0; ks < 2; ++ks)
#pragma unroll
                    for (int nb = 0; nb < 4; ++nb)
                        sacc[mg][nb] = __builtin_amdgcn_mfma_f32_16x16x32_bf16(
                            qf[mg][ks], kf[ks][nb], sacc[mg][nb], 0, 0, 0);
            __builtin_amdgcn_s_setprio(0);

            // --- causal mask (diagonal tile only) ---------------------------
            if (kt == qt) {
#pragma unroll
                for (int mg = 0; mg < 2; ++mg)
#pragma unroll
                    for (int nb = 0; nb < 4; ++nb) {
                        const int col = nb * 16 + laneM;
#pragma unroll
                        for (int r = 0; r < 4; ++r) {
                            const int row = w * 32 + mg * 16 + laneG * 4 + r;
                            if (col > row) sacc[mg][nb][r] = -1e30f;
                        }
                    }
            }

            // --- P = exp2(S*c - 4*log2e) -> per-wave LDS --------------------
            short* Pw = &Pls[w][0];
#pragma unroll
            for (int mg = 0; mg < 2; ++mg)
#pragma unroll
                for (int r = 0; r < 4; ++r)
#pragma unroll
                    for (int nb = 0; nb < 4; ++nb) {
                        const float pv = exp2f(fmaf(sacc[mg][nb][r], cexp, moff));
                        Pw[(mg * 16 + laneG * 4 + r) * 72 + nb * 16 + laneM] = bf16h(pv);
                    }

            // --- V fragments: read ONCE, reuse for both mg ------------------
            bf16x8 vf[2][4];
#pragma unroll
            for (int ks = 0; ks < 2; ++ks)
#pragma unroll
                for (int nb = 0; nb < 4; ++nb) {
                    const int d = nb * 16 + laneM;
                    vf[ks][nb] = *(const bf16x8*)
                        &Vb[d * 64 + (((ks << 2) + laneG) ^ (d & 7)) * 8];
                }

            // --- O += P V ; l += P 1 ----------------------------------------
            __builtin_amdgcn_s_setprio(1);
#pragma unroll
            for (int mg = 0; mg < 2; ++mg)
#pragma unroll
                for (int ks = 0; ks < 2; ++ks) {
                    const bf16x8 pf = *(const bf16x8*)
                        &Pw[(mg * 16 + laneM) * 72 + ks * 32 + laneG * 8];
                    lacc[mg] = __builtin_amdgcn_mfma_f32_16x16x32_bf16(
                        pf, onesb, lacc[mg], 0, 0, 0);
#pragma unroll
                    for (int nb = 0; nb < 4; ++nb)
                        oacc[mg][nb] = __builtin_amdgcn_mfma_f32_16x16x32_bf16(
                            pf, vf[ks][nb], oacc[mg][nb], 0, 0, 0);
                }
            __builtin_amdgcn_s_setprio(0);
        }

        // --- epilogue: y[b*T+q][h*64+d] = O / l -----------------------------
#pragma unroll
        for (int mg = 0; mg < 2; ++mg) {
            short* yp = y + (bT + q0 + w * 32 + mg * 16) * Cc + h * HS;
#pragma unroll
            for (int r = 0; r < 4; ++r) {
                const float inv = 1.f / lacc[mg][r];
#pragma unroll
                for (int nb = 0; nb < 4; ++nb)
                    yp[(size_t)(laneG * 4 + r) * Cc + nb * 16 + laneM] =
                        bf16r(oacc[mg][nb][r] * inv);
            }
        }
    }
}

// ---------------------------------------------------------------------------
// ws layout (shorts): xb[M*C] | WqkvT[3C*C] | WprojT[C*C] | qkv[M*3C] |
//                     yatt[M*C] | vt[M*C]            total ~80 MB
// ---------------------------------------------------------------------------
extern "C" void kernel_launch(void* const* d_in, const int* in_sizes, int n_in,
                              void* d_out, int out_size, void* d_ws, size_t ws_size,
                              hipStream_t stream) {
    const float* x     = (const float*)d_in[0];
    const float* Wqkv  = (const float*)d_in[1];
    const float* bqkv  = (const float*)d_in[2];
    const float* Wproj = (const float*)d_in[3];
    const float* bproj = (const float*)d_in[4];

    constexpr int M = Bb * Tt;                 // 8192
    short* xb     = (short*)d_ws;              // [M, C]
    short* wqkvT  = xb     + (size_t)M * Cc;   // [3C, C]
    short* wprojT = wqkvT  + (size_t)C3 * Cc;  // [C, C]
    short* qkv    = wprojT + (size_t)Cc * Cc;  // [M, 3C]
    short* yatt   = qkv    + (size_t)M * C3;   // [M, C]
    short* vt     = yatt   + (size_t)M * Cc;   // [B*NH*64, T]

    // 0) fused prep: x convert + both weight transposes
    constexpr int PREP_BLOCKS = (M * Cc) / 1024 + (C3 / 32) * (Cc / 32) + (Cc / 32) * (Cc / 32);
    prep_all<<<dim3(PREP_BLOCKS), dim3(256), 0, stream>>>(x, Wqkv, Wproj, xb, wqkvT, wprojT);

    // 1) qkv = x @ Wqkv + bqkv  (bf16 out; 128x128 tile, dbuf, XCD swizzle)
    gemm_mfma_bias<4, 1><<<dim3(C3 / 128, M / 128), dim3(256), 0, stream>>>(
        xb, wqkvT, bqkv, qkv, M, C3, Cc);

    // 1b) vt = V^T  (LDS-tiled, coalesced both sides)
    transpose_v<<<dim3(Tt / 64, Bb * NHh), dim3(256), 0, stream>>>(qkv, vt);

    // 2) flash causal attention: 768 blocks x 128 threads, 2 waves x 32 q-rows,
    //    K/V fragments read once per wave (LDS-BW cut), paired q-tiles, dbuf
    flash_attn<<<dim3(Bb * NHh * 8), dim3(128), 0, stream>>>(qkv, vt, yatt);

    // 3) out = yatt @ Wproj + bproj  (fp32 out; 64x128 tile, dbuf, XCD swizzle)
    gemm_mfma_bias<2, 0><<<dim3(Cc / 128, M / 64), dim3(256), 0, stream>>>(
        yatt, wprojT, bproj, (float*)d_out, M, Cc, Cc);
}

// Round 9
// 182.716 us; speedup vs baseline: 1.0501x; 1.0501x over previous
//
#include <hip/hip_runtime.h>

// Problem constants (reference: B=8, T=1024, C=768, NH=12)
constexpr int Bb  = 8;
constexpr int Tt  = 1024;
constexpr int Cc  = 768;
constexpr int NHh = 12;
constexpr int HS  = 64;        // head size
constexpr int C3  = 3 * Cc;    // 2304

typedef short bf16x8 __attribute__((ext_vector_type(8)));   // 8 bf16 bit-patterns (4 VGPRs)
typedef float f32x4  __attribute__((ext_vector_type(4)));

__device__ inline short bf16r(float f) {           // RNE f32 -> bf16 bits
    unsigned u = __float_as_uint(f);
    u += 0x7FFF + ((u >> 16) & 1);
    return (short)(u >> 16);
}
__device__ inline short bf16h(float f) {           // half-up (cheap, for P in (0,1])
    return (short)((__float_as_uint(f) + 0x8000u) >> 16);
}

// ---------------------------------------------------------------------------
// Fused prep: x fp32->bf16 convert, Wqkv / Wproj fp32->bf16 transpose.
// One launch instead of three (saves 2 launch gaps).
// Sections by blockIdx.x: [0,6144) convert; [6144,7872) Wqkv T; rest Wproj T.
// ---------------------------------------------------------------------------
__global__ __launch_bounds__(256)
void prep_all(const float* __restrict__ x, const float* __restrict__ Wqkv,
              const float* __restrict__ Wproj, short* __restrict__ xb,
              short* __restrict__ wqkvT, short* __restrict__ wprojT) {
    int bid = blockIdx.x;
    constexpr int XBLK = (Bb * Tt * Cc) / 1024;        // 6144
    constexpr int QT   = (C3 / 32) * (Cc / 32);        // 1728
    if (bid < XBLK) {
        const int i = (bid * 256 + threadIdx.x) * 4;
        float4 v = *(const float4*)(x + i);
        short4 o;
        o.x = bf16r(v.x); o.y = bf16r(v.y); o.z = bf16r(v.z); o.w = bf16r(v.w);
        *(short4*)(xb + i) = o;
        return;
    }
    bid -= XBLK;
    const float* src; short* dst; int C;
    if (bid < QT) { src = Wqkv;  dst = wqkvT;  C = C3; }
    else          { bid -= QT; src = Wproj; dst = wprojT; C = Cc; }
    const int tcx = bid % (C / 32), tcy = bid / (C / 32);
    __shared__ short tile[32][33];
    const int tx = threadIdx.x & 31, ty = threadIdx.x >> 5;   // ty 0..7
#pragma unroll
    for (int rr = 0; rr < 4; ++rr) {
        const int r = ty * 4 + rr;
        tile[r][tx] = bf16r(src[(size_t)(tcy * 32 + r) * C + tcx * 32 + tx]);
    }
    __syncthreads();
#pragma unroll
    for (int rr = 0; rr < 4; ++rr) {
        const int orow = ty * 4 + rr;   // output row = input col
        dst[(size_t)(tcx * 32 + orow) * Cc + tcy * 32 + tx] = tile[tx][orow];
    }
}

// ---------------------------------------------------------------------------
// V transpose: qkv V-third [b*T+t][h*64+d] -> vt[(bh*64+d)*T + t]
// 64x64 tiles, 256 threads, 16 elem/thread, 128-B coalesced on both sides.
// (Rounds 1-3: fusing this into the GEMM epilogue always cost more than this
// 5 us kernel.  Round 5: flash_attn NEEDS V staged from this transposed
// layout -- direct global fragment reads are latency death.)
// ---------------------------------------------------------------------------
__global__ __launch_bounds__(256)
void transpose_v(const short* __restrict__ qkv, short* __restrict__ vt) {
    __shared__ short tile[64][65];
    const int bh = blockIdx.y;                 // b*NH + h
    const int b = bh / NHh, h = bh % NHh;
    const int t0 = blockIdx.x * 64;
    const int tx = threadIdx.x & 63, ty = threadIdx.x >> 6;   // ty 0..3
    const short* src = qkv + ((size_t)b * Tt + t0) * C3 + 2 * Cc + h * HS;
#pragma unroll
    for (int r = 0; r < 16; ++r)
        tile[ty * 16 + r][tx] = src[(size_t)(ty * 16 + r) * C3 + tx];
    __syncthreads();
    short* dst = vt + (size_t)bh * HS * Tt + t0;
#pragma unroll
    for (int r = 0; r < 16; ++r)
        dst[(size_t)(ty * 16 + r) * Tt + tx] = tile[tx][ty * 16 + r];
}

// ---------------------------------------------------------------------------
// bf16 MFMA GEMM, double-buffered LDS + XCD-aware block swizzle.
// C[M,N] = A[M,K] @ Bt[N,K]^T + bias.  Tile (MI*32) x 128, BK=32, 4 waves.
// Round-0 exact (VGPR 84): no setprio here -- m190 measured it HURTS the
// barrier-lockstep GEMM structure.  (8-phase 256^2 port is geometry-blocked
// at N=2304: 288 blocks at 1 block/CU -> 56% packing cancels the gain.)
// Requires gridDim.y % 8 == 0.  K % 32 == 0.
// OB: 1 -> bf16 output, 0 -> fp32 output.
// ---------------------------------------------------------------------------
template <int MI, int OB>
__global__ __launch_bounds__(256)
void gemm_mfma_bias(const short* __restrict__ A, const short* __restrict__ Bt,
                    const float* __restrict__ bias, void* __restrict__ Cout,
                    int M, int N, int K) {
    constexpr int TM = MI * 32;
    __shared__ __align__(16) short Als[2][TM * 32];    // [buf][row][k 0..31]
    __shared__ __align__(16) short Bls[2][128 * 32];

    const int t = threadIdx.x, w = t >> 6, lane = t & 63;

    // XCD swizzle
    const int flat = blockIdx.y * gridDim.x + blockIdx.x;
    const int mPer = gridDim.y >> 3;
    const int idx  = flat >> 3;
    const int my   = (flat & 7) * mPer + idx % mPer;
    const int nx   = idx / mPer;
    const int m0 = my * TM, n0 = nx * 128;

    // staging: 4-KB inst = 64 rows x 64 B; thread t -> row t>>2,
    // phys granule t&3, logical granule (t&3)^((t>>3)&3).
    const int sr = t >> 2;                          // 0..63
    const int lg = ((t & 3) ^ ((t >> 3) & 3)) * 8;  // logical granule (shorts)

    const short* Ag[MI / 2];
#pragma unroll
    for (int q = 0; q < MI / 2; ++q)
        Ag[q] = A + (size_t)(m0 + q * 64 + sr) * K + lg;
    const short* Bg[2];
#pragma unroll
    for (int q = 0; q < 2; ++q)
        Bg[q] = Bt + (size_t)(n0 + q * 64 + sr) * K + lg;

    const int wq = w * 1024;   // wave-uniform LDS byte offset within a 4-KB chunk

    const int wm = (w >> 1) * (MI * 16), wn = (w & 1) * 64;
    const int laneM = lane & 15, laneG = lane >> 4;
    // frag-read phys granule: laneG ^ ((row>>1)&3), row ≡ laneM (mod 16)
    const int kx = (laneG ^ ((laneM >> 1) & 3)) * 8;

    f32x4 acc[MI][4] = {};

    const int nk = K / 32;

    // prologue: stage tile 0 into buffer 0
#pragma unroll
    for (int q = 0; q < MI / 2; ++q)
        __builtin_amdgcn_global_load_lds(
            (const __attribute__((address_space(1))) void*)(Ag[q]),
            (__attribute__((address_space(3))) void*)((char*)&Als[0][0] + q * 4096 + wq), 16, 0, 0);
#pragma unroll
    for (int q = 0; q < 2; ++q)
        __builtin_amdgcn_global_load_lds(
            (const __attribute__((address_space(1))) void*)(Bg[q]),
            (__attribute__((address_space(3))) void*)((char*)&Bls[0][0] + q * 4096 + wq), 16, 0, 0);

    for (int kt = 0; kt < nk; ++kt) {
        __syncthreads();   // buf[kt&1] staged; buf[(kt+1)&1] reads (iter kt-1) done

        const short* Ab = &Als[kt & 1][0];
        const short* Bb = &Bls[kt & 1][0];
        bf16x8 af[MI], bfr[4];
#pragma unroll
        for (int i = 0; i < MI; ++i)
            af[i] = *(const bf16x8*)&Ab[(wm + i * 16 + laneM) * 32 + kx];
#pragma unroll
        for (int j = 0; j < 4; ++j)
            bfr[j] = *(const bf16x8*)&Bb[(wn + j * 16 + laneM) * 32 + kx];

        if (kt + 1 < nk) {   // prefetch next tile into the other buffer
            const int b = (kt + 1) & 1, ko = (kt + 1) * 32;
#pragma unroll
            for (int q = 0; q < MI / 2; ++q)
                __builtin_amdgcn_global_load_lds(
                    (const __attribute__((address_space(1))) void*)(Ag[q] + ko),
                    (__attribute__((address_space(3))) void*)((char*)&Als[b][0] + q * 4096 + wq), 16, 0, 0);
#pragma unroll
            for (int q = 0; q < 2; ++q)
                __builtin_amdgcn_global_load_lds(
                    (const __attribute__((address_space(1))) void*)(Bg[q] + ko),
                    (__attribute__((address_space(3))) void*)((char*)&Bls[b][0] + q * 4096 + wq), 16, 0, 0);
        }

#pragma unroll
        for (int i = 0; i < MI; ++i)
#pragma unroll
            for (int j = 0; j < 4; ++j)
                acc[i][j] = __builtin_amdgcn_mfma_f32_16x16x32_bf16(
                    af[i], bfr[j], acc[i][j], 0, 0, 0);
    }

    // epilogue: C/D mapping col = lane&15, row = (lane>>4)*4 + reg
    const int rowBase = m0 + wm + laneG * 4;
    const int colBase = n0 + wn + laneM;
#pragma unroll
    for (int j = 0; j < 4; ++j) {
        const int col = colBase + j * 16;
        const float bv = bias[col];
#pragma unroll
        for (int i = 0; i < MI; ++i) {
#pragma unroll
            for (int r = 0; r < 4; ++r) {
                const int row = rowBase + i * 16 + r;
                const float v = acc[i][j][r] + bv;
                if (OB) ((short*)Cout)[(size_t)row * N + col] = bf16r(v);
                else    ((float*)Cout)[(size_t)row * N + col] = v;
            }
        }
    }
}

// ---------------------------------------------------------------------------
// Flash causal attention, bf16 MFMA, double-buffered K/V staging.
// Round-4 exact -- the measured best (182.44 us total).  Session evidence
// pinning this configuration:
//   r5: V direct-from-global (no LDS)      -> 71 us   (latency death)
//   r6: swapped QK^T + register P repack   -> neutral (bpermute chain = P LDS)
//   r6: occupancy 3->5 blocks/CU           -> null    (not TLP-limited)
//   r7: l off the MFMA pipe (VALU+shfl)    -> neutral-negative
//   r8: 2 waves x 32 rows (half K/V reads) -> 47.7 us (per-wave VALU chain
//       doubled, TLP halved -> issue-bound regression)
// => 4 waves x 16 q-rows with LDS P round-trip and ones-MFMA l is the local
// optimum of this structure.
// Grid = 768 blocks: block (bh, p) does q-tiles p and 15-p sequentially ->
// exactly 17 K-iterations per block (perfect balance, 3 blocks/CU).
// Prefetch of tile kt+1 issued right after the barrier, hidden under the
// 18 MFMAs + softmax of tile kt.  T5 setprio around MFMA clusters (m191).
// Fixed-stabilizer softmax (scores ~N(0,0.31^2), |s|<4 at >10 sigma);
// stabilizer cancels in O/l.  Row-sum l via ones-column MFMA.
// ---------------------------------------------------------------------------
__global__ __launch_bounds__(256)
void flash_attn(const short* __restrict__ qkv, const short* __restrict__ vt,
                short* __restrict__ y) {
    const int bh = blockIdx.x % (Bb * NHh);
    const int pi = blockIdx.x / (Bb * NHh);    // 0..7
    const int h  = bh % NHh, b = bh / NHh;
    const int t = threadIdx.x, w = t >> 6, lane = t & 63;
    const int laneM = lane & 15, laneG = lane >> 4;

    __shared__ short Kls[2][64 * 64];    // [buf][key][d], granule-swizzled
    __shared__ short Vls[2][64 * 64];    // [buf][d][key], granule-swizzled
    __shared__ short Pls[4][16 * 72];    // per-wave P tile [qrow][key]

    const size_t bT = (size_t)b * Tt;

    bf16x8 onesb;
#pragma unroll
    for (int j = 0; j < 8; ++j) onesb[j] = (short)0x3F80;   // bf16 1.0

    const int srow = t >> 3;                  // staging row 0..31 per inst
    const int gpos = t & 7;
    const int gs0 = (gpos ^ (srow & 7)) * 8;  // swizzled granule offset

    const short* Kbase = qkv + (bT + srow) * C3 + Cc + h * HS + gs0;
    const short* Vbase = vt + ((size_t)bh * HS + srow) * Tt + gs0;

    auto stage = [&](int kt, int buf) {
        const short* Kg = Kbase + (size_t)kt * 64 * C3;
        const short* Vg = Vbase + kt * 64;
        char* KB = (char*)&Kls[buf][0] + w * 1024;
        char* VB = (char*)&Vls[buf][0] + w * 1024;
        __builtin_amdgcn_global_load_lds(
            (const __attribute__((address_space(1))) void*)Kg,
            (__attribute__((address_space(3))) void*)(KB), 16, 0, 0);
        __builtin_amdgcn_global_load_lds(
            (const __attribute__((address_space(1))) void*)(Kg + 32 * C3),
            (__attribute__((address_space(3))) void*)(KB + 4096), 16, 0, 0);
        __builtin_amdgcn_global_load_lds(
            (const __attribute__((address_space(1))) void*)Vg,
            (__attribute__((address_space(3))) void*)(VB), 16, 0, 0);
        __builtin_amdgcn_global_load_lds(
            (const __attribute__((address_space(1))) void*)(Vg + 32 * Tt),
            (__attribute__((address_space(3))) void*)(VB + 4096), 16, 0, 0);
    };

    constexpr float cexp = 0.18033688f;       // (1/sqrt(64)) * log2(e)
    constexpr float moff = -5.7707801f;       // -4 * log2(e)

#pragma unroll 1
    for (int sub = 0; sub < 2; ++sub) {
        const int qt = sub ? (15 - pi) : pi;
        const int q0 = qt * 64;

        const short* qp = qkv + (bT + q0 + w * 16 + laneM) * C3 + h * HS;
        const bf16x8 qf0 = *(const bf16x8*)(qp + laneG * 8);
        const bf16x8 qf1 = *(const bf16x8*)(qp + 32 + laneG * 8);

        f32x4 oacc[4] = {};
        f32x4 lacc   = {};

        __syncthreads();       // prior sub's reads of buf0 done before restage
        stage(0, 0);           // prologue

#pragma unroll 1
        for (int kt = 0; kt <= qt; ++kt) {
            __syncthreads();   // buf[kt&1] staged; other buf's reads done
            if (kt < qt) stage(kt + 1, (kt + 1) & 1);

            const short* Kb = &Kls[kt & 1][0];
            const short* Vb = &Vls[kt & 1][0];

            // --- S = Q K^T ---------------------------------------------------
            f32x4 sacc[4] = {};
            __builtin_amdgcn_s_setprio(1);
#pragma unroll
            for (int ks = 0; ks < 2; ++ks) {
                const bf16x8 qf = ks ? qf1 : qf0;
#pragma unroll
                for (int nb = 0; nb < 4; ++nb) {
                    const int key = nb * 16 + laneM;
                    const bf16x8 kf = *(const bf16x8*)
                        &Kb[key * 64 + (((ks << 2) + laneG) ^ (key & 7)) * 8];
                    sacc[nb] = __builtin_amdgcn_mfma_f32_16x16x32_bf16(
                        qf, kf, sacc[nb], 0, 0, 0);
                }
            }
            __builtin_amdgcn_s_setprio(0);

            // --- causal mask (diagonal tile only) ---------------------------
            if (kt == qt) {
#pragma unroll
                for (int nb = 0; nb < 4; ++nb) {
                    const int col = nb * 16 + laneM;
#pragma unroll
                    for (int r = 0; r < 4; ++r) {
                        const int row = w * 16 + laneG * 4 + r;
                        if (col > row) sacc[nb][r] = -1e30f;
                    }
                }
            }

            // --- P = exp2(S*c - 4*log2e) -> per-wave LDS --------------------
            short* Pw = &Pls[w][0];
#pragma unroll
            for (int r = 0; r < 4; ++r)
#pragma unroll
                for (int nb = 0; nb < 4; ++nb) {
                    const float pv = exp2f(fmaf(sacc[nb][r], cexp, moff));
                    Pw[(laneG * 4 + r) * 72 + nb * 16 + laneM] = bf16h(pv);
                }

            // --- O += P V ; l += P 1 ----------------------------------------
            __builtin_amdgcn_s_setprio(1);
#pragma unroll
            for (int ks = 0; ks < 2; ++ks) {
                const bf16x8 pf = *(const bf16x8*)&Pw[laneM * 72 + ks * 32 + laneG * 8];
                lacc = __builtin_amdgcn_mfma_f32_16x16x32_bf16(pf, onesb, lacc, 0, 0, 0);
#pragma unroll
                for (int nb = 0; nb < 4; ++nb) {
                    const int d = nb * 16 + laneM;
                    const bf16x8 vf = *(const bf16x8*)
                        &Vb[d * 64 + (((ks << 2) + laneG) ^ (d & 7)) * 8];
                    oacc[nb] = __builtin_amdgcn_mfma_f32_16x16x32_bf16(
                        pf, vf, oacc[nb], 0, 0, 0);
                }
            }
            __builtin_amdgcn_s_setprio(0);
        }

        // --- epilogue: y[b*T+q][h*64+d] = O / l -----------------------------
        short* yp = y + (bT + q0 + w * 16) * Cc + h * HS;
#pragma unroll
        for (int r = 0; r < 4; ++r) {
            const float inv = 1.f / lacc[r];
#pragma unroll
            for (int nb = 0; nb < 4; ++nb)
                yp[(size_t)(laneG * 4 + r) * Cc + nb * 16 + laneM] = bf16r(oacc[nb][r] * inv);
        }
    }
}

// ---------------------------------------------------------------------------
// ws layout (shorts): xb[M*C] | WqkvT[3C*C] | WprojT[C*C] | qkv[M*3C] |
//                     yatt[M*C] | vt[M*C]            total ~80 MB
// ---------------------------------------------------------------------------
extern "C" void kernel_launch(void* const* d_in, const int* in_sizes, int n_in,
                              void* d_out, int out_size, void* d_ws, size_t ws_size,
                              hipStream_t stream) {
    const float* x     = (const float*)d_in[0];
    const float* Wqkv  = (const float*)d_in[1];
    const float* bqkv  = (const float*)d_in[2];
    const float* Wproj = (const float*)d_in[3];
    const float* bproj = (const float*)d_in[4];

    constexpr int M = Bb * Tt;                 // 8192
    short* xb     = (short*)d_ws;              // [M, C]
    short* wqkvT  = xb     + (size_t)M * Cc;   // [3C, C]
    short* wprojT = wqkvT  + (size_t)C3 * Cc;  // [C, C]
    short* qkv    = wprojT + (size_t)Cc * Cc;  // [M, 3C]
    short* yatt   = qkv    + (size_t)M * C3;   // [M, C]
    short* vt     = yatt   + (size_t)M * Cc;   // [B*NH*64, T]

    // 0) fused prep: x convert + both weight transposes
    constexpr int PREP_BLOCKS = (M * Cc) / 1024 + (C3 / 32) * (Cc / 32) + (Cc / 32) * (Cc / 32);
    prep_all<<<dim3(PREP_BLOCKS), dim3(256), 0, stream>>>(x, Wqkv, Wproj, xb, wqkvT, wprojT);

    // 1) qkv = x @ Wqkv + bqkv  (bf16 out; 128x128 tile, dbuf, XCD swizzle)
    gemm_mfma_bias<4, 1><<<dim3(C3 / 128, M / 128), dim3(256), 0, stream>>>(
        xb, wqkvT, bqkv, qkv, M, C3, Cc);

    // 1b) vt = V^T  (LDS-tiled, coalesced both sides)
    transpose_v<<<dim3(Tt / 64, Bb * NHh), dim3(256), 0, stream>>>(qkv, vt);

    // 2) flash causal attention (bf16 in/out), paired q-tiles, dbuf K/V
    flash_attn<<<dim3(Bb * NHh * 8), dim3(256), 0, stream>>>(qkv, vt, yatt);

    // 3) out = yatt @ Wproj + bproj  (fp32 out; 64x128 tile, dbuf, XCD swizzle)
    gemm_mfma_bias<2, 0><<<dim3(Cc / 128, M / 64), dim3(256), 0, stream>>>(
        yatt, wprojT, bproj, (float*)d_out, M, Cc, Cc);
}